// Round 1
// baseline (426.687 us; speedup 1.0000x reference)
//
#include <hip/hip_runtime.h>
#include <math.h>

#define B_ 8
#define H_ 128
#define W_ 128
#define C_ 3
#define D_ 132
#define HW_ (H_*W_)            // 16384
#define RPB_ (HW_+1)           // 16385 rows per batch (incl. zero row)
#define NROWS_ (B_*RPB_)       // 131080
#define NK_ (2048*32)          // 65536 gathers per batch per side
#define NOUT_ (B_*NK_)         // 524288 outputs

// ---------------------------------------------------------------------------
// K0: M = Ks^T Qs (132x132), u = Ks^T b_q, v = Qs^T b_k, c = b_k . b_q
// ---------------------------------------------------------------------------
__global__ __launch_bounds__(256) void prep_kernel(
    const float* __restrict__ ks_w, const float* __restrict__ ks_b,
    const float* __restrict__ qs_w, const float* __restrict__ qs_b,
    float* __restrict__ Mm, float* __restrict__ u, float* __restrict__ v,
    float* __restrict__ cc) {
  int idx = blockIdx.x * 256 + threadIdx.x;
  if (idx < D_ * D_) {
    int a = idx / D_, bb = idx - a * D_;
    float s = 0.f;
    for (int i = 0; i < D_; ++i)
      s = fmaf(ks_w[i * D_ + a], qs_w[i * D_ + bb], s);
    Mm[idx] = s;
  }
  if (idx < D_) {
    float s1 = 0.f, s2 = 0.f;
    for (int i = 0; i < D_; ++i) {
      s1 = fmaf(qs_b[i], ks_w[i * D_ + idx], s1);
      s2 = fmaf(ks_b[i], qs_w[i * D_ + idx], s2);
    }
    u[idx] = s1;
    v[idx] = s2;
  }
  if (idx == 0) {
    float s = 0.f;
    for (int i = 0; i < D_; ++i) s = fmaf(ks_b[i], qs_b[i], s);
    cc[0] = s;
  }
}

// ---------------------------------------------------------------------------
// K1: 3x3 SAME conv + bias, then L2-normalize over the W axis (per b,d,h),
// write transposed layout flat[b*16385 + h*128 + w][d].
// One block per (b, h). Last block zeroes the per-batch zero rows.
// ---------------------------------------------------------------------------
__global__ __launch_bounds__(256) void conv_norm_kernel(
    const float* __restrict__ img, const float* __restrict__ cw,
    const float* __restrict__ cb, float* __restrict__ flat) {
  int bid = blockIdx.x;
  if (bid >= B_ * H_) {
    // zero row 16384 of every batch
    for (int i = threadIdx.x; i < B_ * D_; i += 256) {
      int b = i / D_, d = i - (i / D_) * D_;
      flat[((size_t)b * RPB_ + HW_) * D_ + d] = 0.f;
    }
    return;
  }
  int b = bid >> 7, h = bid & 127;

  __shared__ float in_s[C_][3][W_ + 2];   // 3*3*130
  __shared__ float w_s[D_ * 27];
  __shared__ float b_s[D_];
  __shared__ float sval[D_ * (W_ + 1)];   // padded stride 129
  __shared__ float nscale[D_];

  // load input rows h-1..h+1 (zero-padded), cols -1..128
  for (int i = threadIdx.x; i < C_ * 3 * (W_ + 2); i += 256) {
    int c = i / (3 * (W_ + 2));
    int rem = i - c * (3 * (W_ + 2));
    int r = rem / (W_ + 2);
    int x = rem - r * (W_ + 2);
    int hh = h + r - 1;
    int ww = x - 1;
    float val = 0.f;
    if (hh >= 0 && hh < H_ && ww >= 0 && ww < W_)
      val = img[((size_t)(b * C_ + c) * H_ + hh) * W_ + ww];
    in_s[c][r][x] = val;
  }
  for (int i = threadIdx.x; i < D_ * 27; i += 256) w_s[i] = cw[i];
  if (threadIdx.x < D_) b_s[threadIdx.x] = cb[threadIdx.x];
  __syncthreads();

  // conv: sval[d][w]
  for (int i = threadIdx.x; i < D_ * W_; i += 256) {
    int d = i >> 7, w = i & 127;
    float acc = b_s[d];
    const float* wp = &w_s[d * 27];
#pragma unroll
    for (int c = 0; c < 3; ++c)
#pragma unroll
      for (int kh = 0; kh < 3; ++kh) {
        acc = fmaf(in_s[c][kh][w + 0], wp[(c * 3 + kh) * 3 + 0], acc);
        acc = fmaf(in_s[c][kh][w + 1], wp[(c * 3 + kh) * 3 + 1], acc);
        acc = fmaf(in_s[c][kh][w + 2], wp[(c * 3 + kh) * 3 + 2], acc);
      }
    sval[d * (W_ + 1) + w] = acc;
  }
  __syncthreads();

  // L2 norm over w for each d
  if (threadIdx.x < D_) {
    int d = threadIdx.x;
    float ssq = 0.f;
    for (int w = 0; w < W_; ++w) {
      float t = sval[d * (W_ + 1) + w];
      ssq = fmaf(t, t, ssq);
    }
    float nrm = sqrtf(ssq);
    nscale[d] = 1.f / fmaxf(nrm, 1e-12f);
  }
  __syncthreads();

  // write normalized, transposed: flat[row][d], row = b*16385 + h*128 + w
  size_t rowbase = (size_t)b * RPB_ + (size_t)h * W_;
  for (int i = threadIdx.x; i < W_ * D_; i += 256) {
    int w = i / D_;
    int d = i - w * D_;
    flat[(rowbase + w) * D_ + d] = sval[d * (W_ + 1) + w] * nscale[d];
  }
}

// ---------------------------------------------------------------------------
// K2: z = flat @ M^T  (rows = 131080, K = N = 132), plus su = flat.u, sv = flat.v
// 64-row tiles; flat tile + full M in LDS; 4x6 register micro-tiles.
// ---------------------------------------------------------------------------
__global__ __launch_bounds__(256) void gemm_kernel(
    const float* __restrict__ flat, const float* __restrict__ Mm,
    const float* __restrict__ u, const float* __restrict__ v,
    float* __restrict__ z, float* __restrict__ su, float* __restrict__ sv) {
  __shared__ float fs[64 * 133];
  __shared__ float ms[D_ * 133];
  __shared__ float us[D_], vs[D_];
  size_t row0 = (size_t)blockIdx.x * 64;

  for (int i = threadIdx.x; i < D_ * D_; i += 256) {
    int a = i / D_, bb = i - (i / D_) * D_;
    ms[a * 133 + bb] = Mm[i];
  }
  for (int i = threadIdx.x; i < 64 * D_; i += 256) {
    int r = i / D_, bb = i - (i / D_) * D_;
    size_t rr = row0 + r;
    fs[r * 133 + bb] = (rr < NROWS_) ? flat[rr * D_ + bb] : 0.f;
  }
  if (threadIdx.x < D_) {
    us[threadIdx.x] = u[threadIdx.x];
    vs[threadIdx.x] = v[threadIdx.x];
  }
  __syncthreads();

  // 16 row-groups x 22 col-groups = 352 tiles of 4 rows x 6 cols
  for (int tile = threadIdx.x; tile < 352; tile += 256) {
    int rg = tile / 22, cg = tile - rg * 22;
    int r0 = rg * 4, a0 = cg * 6;
    float acc[4][6] = {};
#pragma unroll 4
    for (int bb = 0; bb < D_; ++bb) {
      float fv[4], mv[6];
#pragma unroll
      for (int i2 = 0; i2 < 4; ++i2) fv[i2] = fs[(r0 + i2) * 133 + bb];
#pragma unroll
      for (int j = 0; j < 6; ++j) mv[j] = ms[(a0 + j) * 133 + bb];
#pragma unroll
      for (int i2 = 0; i2 < 4; ++i2)
#pragma unroll
        for (int j = 0; j < 6; ++j)
          acc[i2][j] = fmaf(fv[i2], mv[j], acc[i2][j]);
    }
#pragma unroll
    for (int i2 = 0; i2 < 4; ++i2) {
      size_t rr = row0 + r0 + i2;
      if (rr < NROWS_) {
#pragma unroll
        for (int j = 0; j < 6; ++j)
          z[rr * D_ + a0 + j] = acc[i2][j];
      }
    }
  }

  // su / sv for this tile's rows
  if (threadIdx.x < 128) {
    int r = threadIdx.x & 63;
    size_t rr = row0 + r;
    if (rr < NROWS_) {
      const float* coef = (threadIdx.x < 64) ? us : vs;
      float s = 0.f;
      for (int bb = 0; bb < D_; ++bb) s = fmaf(coef[bb], fs[r * 133 + bb], s);
      if (threadIdx.x < 64) su[rr] = s; else sv[rr] = s;
    }
  }
}

// ---------------------------------------------------------------------------
// K3: gather + dot. 8 lanes per output; float4 loads (132 floats = 33 float4).
// out[b,n,k] = (flat[x] . z[y] + su[x] + sv[y] + c) * 132^-0.5
// ---------------------------------------------------------------------------
__global__ __launch_bounds__(256) void gather_kernel(
    const int* __restrict__ xi, const int* __restrict__ yi,
    const float* __restrict__ flat, const float* __restrict__ z,
    const float* __restrict__ su, const float* __restrict__ sv,
    const float* __restrict__ cc, float* __restrict__ out) {
  const float scale = 0.08703882797784892f;  // 132^-0.5
  int o = blockIdx.x * 32 + (threadIdx.x >> 3);
  int lane = threadIdx.x & 7;
  int b = o >> 16;          // NK_ = 65536
  int rem = o & 65535;
  int x = xi[(size_t)b * NK_ + rem];
  int y = yi[(size_t)b * NK_ + rem];
  const float4* fx = (const float4*)&flat[((size_t)b * RPB_ + x) * D_];
  const float4* zy = (const float4*)&z[((size_t)b * RPB_ + y) * D_];
  float acc = 0.f;
#pragma unroll
  for (int m = 0; m < 4; ++m) {
    float4 a4 = fx[lane + m * 8];
    float4 b4 = zy[lane + m * 8];
    acc = fmaf(a4.x, b4.x, acc);
    acc = fmaf(a4.y, b4.y, acc);
    acc = fmaf(a4.z, b4.z, acc);
    acc = fmaf(a4.w, b4.w, acc);
  }
  if (lane == 0) {  // elements 128..131
    float4 a4 = fx[32];
    float4 b4 = zy[32];
    acc = fmaf(a4.x, b4.x, acc);
    acc = fmaf(a4.y, b4.y, acc);
    acc = fmaf(a4.z, b4.z, acc);
    acc = fmaf(a4.w, b4.w, acc);
  }
  acc += __shfl_xor(acc, 1);
  acc += __shfl_xor(acc, 2);
  acc += __shfl_xor(acc, 4);
  if (lane == 0) {
    float tot = acc + su[(size_t)b * RPB_ + x] + sv[(size_t)b * RPB_ + y] + cc[0];
    out[o] = tot * scale;
  }
}

// ---------------------------------------------------------------------------
extern "C" void kernel_launch(void* const* d_in, const int* in_sizes, int n_in,
                              void* d_out, int out_size, void* d_ws, size_t ws_size,
                              hipStream_t stream) {
  const int* indices  = (const int*)d_in[0];
  const float* img    = (const float*)d_in[1];
  const float* conv_w = (const float*)d_in[2];
  const float* conv_b = (const float*)d_in[3];
  const float* ks_w   = (const float*)d_in[4];
  const float* ks_b   = (const float*)d_in[5];
  const float* qs_w   = (const float*)d_in[6];
  const float* qs_b   = (const float*)d_in[7];
  float* out = (float*)d_out;

  // workspace layout (f32): ~139.6 MB total
  float* flat = (float*)d_ws;                    // NROWS_*132
  float* z    = flat + (size_t)NROWS_ * D_;      // NROWS_*132
  float* su   = z + (size_t)NROWS_ * D_;         // NROWS_
  float* sv   = su + NROWS_;                     // NROWS_
  float* Mm   = sv + NROWS_;                     // 132*132
  float* u    = Mm + D_ * D_;                    // 132
  float* v    = u + D_;                          // 132
  float* cc   = v + D_;                          // 1

  const int* xi = indices + (size_t)B_ * NK_;      // indices[1]
  const int* yi = indices + (size_t)2 * B_ * NK_;  // indices[2]

  hipLaunchKernelGGL(prep_kernel, dim3(69), dim3(256), 0, stream,
                     ks_w, ks_b, qs_w, qs_b, Mm, u, v, cc);
  hipLaunchKernelGGL(conv_norm_kernel, dim3(B_ * H_ + 1), dim3(256), 0, stream,
                     img, conv_w, conv_b, flat);
  hipLaunchKernelGGL(gemm_kernel, dim3((NROWS_ + 63) / 64), dim3(256), 0, stream,
                     flat, Mm, u, v, z, su, sv);
  hipLaunchKernelGGL(gather_kernel, dim3(NOUT_ / 32), dim3(256), 0, stream,
                     xi, yi, flat, z, su, sv, cc, out);
}

// Round 2
// 174.442 us; speedup vs baseline: 2.4460x; 2.4460x over previous
//
#include <hip/hip_runtime.h>
#include <hip/hip_bf16.h>
#include <math.h>

#define B_ 8
#define H_ 128
#define W_ 128
#define C_ 3
#define D_ 132
#define HW_ (H_*W_)            // 16384
#define RPB_ (HW_+1)           // 16385 rows per batch (incl. zero row)
#define NROWS_ (B_*RPB_)       // 131080
#define AROWS_ 131136          // rows incl. slack so last 64-row tile can stage
#define FSTRIDE_ 168           // bf16 row stride (336 B = 21*16, bank-friendly)
#define ZSTRIDE_ 132           // f32 z row stride
#define NK_ 65536
#define NOUT_ (B_*NK_)         // 524288
#define MELEMS_ 24576          // M buffer elems (49152 B = 48 chunks of 1 KiB)

typedef __attribute__((ext_vector_type(8))) short short8v;
typedef __attribute__((ext_vector_type(8))) unsigned short ushort8v;
typedef __attribute__((ext_vector_type(4))) float f32x4;

#define GLOAD16(gp, lp) __builtin_amdgcn_global_load_lds( \
  (const __attribute__((address_space(1))) unsigned int*)(gp), \
  (__attribute__((address_space(3))) unsigned int*)(void*)(lp), 16, 0, 0)

__device__ inline float bf2f(unsigned short u) {
  return __uint_as_float(((unsigned)u) << 16);
}

// ---------------------------------------------------------------------------
// K0: M_bf16[a][k] (a = x-side col, k = y-side col), padded [146+][168].
//   a<132:  M[a][k] = sum_o ks_w[o][a] * qs_w[o][k]
//   a==132: u[k]    = sum_o qs_b[o] * ks_w[o][k]   (makes z col 132 = su)
//   a==133: v[k]    = sum_o ks_b[o] * qs_w[o][k]   (makes z col 133 = sv)
//   else 0. Also c = ks_b . qs_b (f32).
// ---------------------------------------------------------------------------
__global__ __launch_bounds__(256) void prep_kernel(
    const float* __restrict__ ks_w, const float* __restrict__ ks_b,
    const float* __restrict__ qs_w, const float* __restrict__ qs_b,
    unsigned short* __restrict__ Mb, float* __restrict__ cc) {
  int idx = blockIdx.x * 256 + threadIdx.x;
  if (idx >= MELEMS_) return;
  int a = idx / FSTRIDE_;
  int k = idx - a * FSTRIDE_;
  float val = 0.f;
  if (k < D_) {
    if (a < D_) {
      for (int o = 0; o < D_; ++o)
        val = fmaf(ks_w[o * D_ + a], qs_w[o * D_ + k], val);
    } else if (a == 132) {
      for (int o = 0; o < D_; ++o)
        val = fmaf(qs_b[o], ks_w[o * D_ + k], val);
    } else if (a == 133) {
      for (int o = 0; o < D_; ++o)
        val = fmaf(ks_b[o], qs_w[o * D_ + k], val);
    }
  }
  __hip_bfloat16 hb = __float2bfloat16(val);
  Mb[idx] = *(unsigned short*)&hb;
  if (idx == 0) {
    float s = 0.f;
    for (int o = 0; o < D_; ++o) s = fmaf(ks_b[o], qs_b[o], s);
    cc[0] = s;
  }
}

// ---------------------------------------------------------------------------
// K1: 3x3 SAME conv + bias, L2-normalize over W axis (per b,d,h), write
// bf16 transposed flat[row][d], row = b*16385 + h*128 + w, stride 168.
// ---------------------------------------------------------------------------
__global__ __launch_bounds__(256) void conv_norm_kernel(
    const float* __restrict__ img, const float* __restrict__ cw,
    const float* __restrict__ cb, unsigned short* __restrict__ flat) {
  int bid = blockIdx.x;
  if (bid >= B_ * H_) {
    // zero row 16384 of every batch (cols 0..131; pad cols never used)
    for (int i = threadIdx.x; i < B_ * D_; i += 256) {
      int b = i / D_, d = i - (i / D_) * D_;
      flat[((size_t)b * RPB_ + HW_) * FSTRIDE_ + d] = 0;
    }
    return;
  }
  int b = bid >> 7, h = bid & 127;

  __shared__ float in_s[C_][3][W_ + 2];
  __shared__ float w_s[D_ * 27];
  __shared__ float b_s[D_];
  __shared__ float sval[D_ * (W_ + 1)];
  __shared__ float nscale[D_];

  for (int i = threadIdx.x; i < C_ * 3 * (W_ + 2); i += 256) {
    int c = i / (3 * (W_ + 2));
    int rem = i - c * (3 * (W_ + 2));
    int r = rem / (W_ + 2);
    int x = rem - r * (W_ + 2);
    int hh = h + r - 1;
    int ww = x - 1;
    float val = 0.f;
    if (hh >= 0 && hh < H_ && ww >= 0 && ww < W_)
      val = img[((size_t)(b * C_ + c) * H_ + hh) * W_ + ww];
    in_s[c][r][x] = val;
  }
  for (int i = threadIdx.x; i < D_ * 27; i += 256) w_s[i] = cw[i];
  if (threadIdx.x < D_) b_s[threadIdx.x] = cb[threadIdx.x];
  __syncthreads();

  for (int i = threadIdx.x; i < D_ * W_; i += 256) {
    int d = i >> 7, w = i & 127;
    float acc = b_s[d];
    const float* wp = &w_s[d * 27];
#pragma unroll
    for (int c = 0; c < 3; ++c)
#pragma unroll
      for (int kh = 0; kh < 3; ++kh) {
        acc = fmaf(in_s[c][kh][w + 0], wp[(c * 3 + kh) * 3 + 0], acc);
        acc = fmaf(in_s[c][kh][w + 1], wp[(c * 3 + kh) * 3 + 1], acc);
        acc = fmaf(in_s[c][kh][w + 2], wp[(c * 3 + kh) * 3 + 2], acc);
      }
    sval[d * (W_ + 1) + w] = acc;
  }
  __syncthreads();

  if (threadIdx.x < D_) {
    int d = threadIdx.x;
    float ssq = 0.f;
    for (int w = 0; w < W_; ++w) {
      float t = sval[d * (W_ + 1) + w];
      ssq = fmaf(t, t, ssq);
    }
    nscale[d] = 1.f / fmaxf(sqrtf(ssq), 1e-12f);
  }
  __syncthreads();

  size_t rowbase = (size_t)b * RPB_ + (size_t)h * W_;
  for (int i = threadIdx.x; i < W_ * D_; i += 256) {
    int w = i / D_;
    int d = i - w * D_;
    float val = sval[d * (W_ + 1) + w] * nscale[d];
    __hip_bfloat16 hb = __float2bfloat16(val);
    flat[(rowbase + w) * FSTRIDE_ + d] = *(unsigned short*)&hb;
  }
}

// ---------------------------------------------------------------------------
// K2: MFMA GEMM. z[r][c] = sum_k flat[r][k] * M[c][k]  (c<132),
//     su[r] = z-col 132, sv[r] = z-col 133.
// 64 rows/block, 4 waves x (16 rows x 144 cols), K = 5 slices of 32.
// A tile + full M staged via global_load_lds (pre-padded layouts).
// ---------------------------------------------------------------------------
__global__ __launch_bounds__(256, 2) void gemm_kernel(
    const unsigned short* __restrict__ fb, const unsigned short* __restrict__ Mb,
    float* __restrict__ z, float* __restrict__ su, float* __restrict__ sv) {
  __shared__ unsigned short As[64 * FSTRIDE_];  // 21504 B
  __shared__ unsigned short Ms[MELEMS_];        // 49152 B
  int tid = threadIdx.x, wave = tid >> 6, lane = tid & 63;
  size_t row0 = (size_t)blockIdx.x * 64;

  // stage M: 48 chunks of 1 KiB (L2-broadcast)
  for (int ch = wave; ch < 48; ch += 4)
    GLOAD16(Mb + (size_t)ch * 512 + lane * 8, Ms + ch * 512);
  // stage A: 21 chunks of 1 KiB
  const unsigned short* Ag = fb + row0 * FSTRIDE_;
  for (int ch = wave; ch < 21; ch += 4)
    GLOAD16(Ag + (size_t)ch * 512 + lane * 8, As + ch * 512);
  __syncthreads();

  int c15 = lane & 15, kg = lane >> 4;
  const unsigned short* arow = &As[(wave * 16 + c15) * FSTRIDE_ + kg * 8];
  const unsigned short* brow = &Ms[c15 * FSTRIDE_ + kg * 8];
  f32x4 acc[9] = {};
#pragma unroll
  for (int ks = 0; ks < 5; ++ks) {
    short8v af = *(const short8v*)(arow + ks * 32);
#pragma unroll
    for (int ct = 0; ct < 9; ++ct) {
      short8v bf = *(const short8v*)(brow + ct * 16 * FSTRIDE_ + ks * 32);
      acc[ct] = __builtin_amdgcn_mfma_f32_16x16x32_bf16(af, bf, acc[ct], 0, 0, 0);
    }
  }

  // C/D layout: col = lane&15, row = (lane>>4)*4 + reg
  size_t rbase = row0 + wave * 16 + kg * 4;
#pragma unroll
  for (int ct = 0; ct < 9; ++ct) {
    int col = ct * 16 + c15;
#pragma unroll
    for (int j = 0; j < 4; ++j) {
      size_t r = rbase + j;
      if (r < NROWS_) {
        if (col < ZSTRIDE_)      z[r * ZSTRIDE_ + col] = acc[ct][j];
        else if (col == 132)     su[r] = acc[ct][j];
        else if (col == 133)     sv[r] = acc[ct][j];
      }
    }
  }
}

// ---------------------------------------------------------------------------
// K3: gather + dot. 8 lanes per output.
// out = (flat_bf16[x] . z[y] + su[x] + sv[y] + c) * 132^-0.5
// ---------------------------------------------------------------------------
__global__ __launch_bounds__(256) void gather_kernel(
    const int* __restrict__ xi, const int* __restrict__ yi,
    const unsigned short* __restrict__ flat, const float* __restrict__ z,
    const float* __restrict__ su, const float* __restrict__ sv,
    const float* __restrict__ cc, float* __restrict__ out) {
  const float scale = 0.08703882797784892f;  // 132^-0.5
  int o = blockIdx.x * 32 + (threadIdx.x >> 3);
  int lane = threadIdx.x & 7;
  int b = o >> 16;
  int rem = o & 65535;
  size_t ib = (size_t)b * NK_ + rem;
  int x = xi[ib], y = yi[ib];
  size_t rx = (size_t)b * RPB_ + x;
  size_t ry = (size_t)b * RPB_ + y;
  const unsigned short* fx = flat + rx * FSTRIDE_;
  const float* zy = z + ry * ZSTRIDE_;
  float acc = 0.f;
#pragma unroll
  for (int leg = 0; leg < 2; ++leg) {
    int e0 = leg * 64 + lane * 8;
    ushort8v a8 = *(const ushort8v*)(fx + e0);
    float4 z0 = *(const float4*)(zy + e0);
    float4 z1 = *(const float4*)(zy + e0 + 4);
    acc = fmaf(bf2f(a8[0]), z0.x, acc);
    acc = fmaf(bf2f(a8[1]), z0.y, acc);
    acc = fmaf(bf2f(a8[2]), z0.z, acc);
    acc = fmaf(bf2f(a8[3]), z0.w, acc);
    acc = fmaf(bf2f(a8[4]), z1.x, acc);
    acc = fmaf(bf2f(a8[5]), z1.y, acc);
    acc = fmaf(bf2f(a8[6]), z1.z, acc);
    acc = fmaf(bf2f(a8[7]), z1.w, acc);
  }
  if (lane == 0) {  // elems 128..131
    ushort8v a8 = *(const ushort8v*)(fx + 128);
    float4 z0 = *(const float4*)(zy + 128);
    acc = fmaf(bf2f(a8[0]), z0.x, acc);
    acc = fmaf(bf2f(a8[1]), z0.y, acc);
    acc = fmaf(bf2f(a8[2]), z0.z, acc);
    acc = fmaf(bf2f(a8[3]), z0.w, acc);
  }
  acc += __shfl_xor(acc, 1);
  acc += __shfl_xor(acc, 2);
  acc += __shfl_xor(acc, 4);
  if (lane == 0)
    out[o] = (acc + su[rx] + sv[ry] + cc[0]) * scale;
}

// ---------------------------------------------------------------------------
extern "C" void kernel_launch(void* const* d_in, const int* in_sizes, int n_in,
                              void* d_out, int out_size, void* d_ws, size_t ws_size,
                              hipStream_t stream) {
  const int* indices  = (const int*)d_in[0];
  const float* img    = (const float*)d_in[1];
  const float* conv_w = (const float*)d_in[2];
  const float* conv_b = (const float*)d_in[3];
  const float* ks_w   = (const float*)d_in[4];
  const float* ks_b   = (const float*)d_in[5];
  const float* qs_w   = (const float*)d_in[6];
  const float* qs_b   = (const float*)d_in[7];
  float* out = (float*)d_out;

  // workspace layout (~114.4 MB)
  char* w = (char*)d_ws;
  unsigned short* flatb = (unsigned short*)w;                 // AROWS_*168 bf16
  size_t off = (size_t)AROWS_ * FSTRIDE_ * 2;                 // 44,061,696
  float* z = (float*)(w + off);  off += (size_t)NROWS_ * ZSTRIDE_ * 4;  // 69,210,240
  float* su = (float*)(w + off); off += (size_t)NROWS_ * 4;   // 524,320
  float* sv = (float*)(w + off); off += (size_t)NROWS_ * 4;   // 524,320
  unsigned short* Mb = (unsigned short*)(w + off); off += MELEMS_ * 2;  // 49,152
  float* cc = (float*)(w + off);

  const int* xi = indices + (size_t)B_ * NK_;      // indices[1]
  const int* yi = indices + (size_t)2 * B_ * NK_;  // indices[2]

  hipLaunchKernelGGL(prep_kernel, dim3(MELEMS_ / 256), dim3(256), 0, stream,
                     ks_w, ks_b, qs_w, qs_b, Mb, cc);
  hipLaunchKernelGGL(conv_norm_kernel, dim3(B_ * H_ + 1), dim3(256), 0, stream,
                     img, conv_w, conv_b, flatb);
  hipLaunchKernelGGL(gemm_kernel, dim3((NROWS_ + 63) / 64), dim3(256), 0, stream,
                     flatb, Mb, z, su, sv);
  hipLaunchKernelGGL(gather_kernel, dim3(NOUT_ / 32), dim3(256), 0, stream,
                     xi, yi, flatb, z, su, sv, cc, out);
}

// Round 3
// 124.568 us; speedup vs baseline: 3.4253x; 1.4004x over previous
//
#include <hip/hip_runtime.h>
#include <hip/hip_bf16.h>
#include <math.h>

#define B_ 8
#define H_ 128
#define W_ 128
#define C_ 3
#define D_ 132
#define HW_ (H_*W_)            // 16384
#define RPB_ (HW_+1)           // 16385 rows per batch (incl. zero row)
#define NROWS_ (B_*RPB_)       // 131080
#define AROWS_ 131136          // rows incl. slack so last 64-row tile can stage
#define FSTRIDE_ 168           // bf16 row stride (336 B = 21*16, bank-friendly)
#define ZSTRIDE_ 132           // f32 z row stride
#define NK_ 65536
#define NOUT_ (B_*NK_)         // 524288
#define MELEMS_ 24576          // M buffer elems (49152 B = 48 chunks of 1 KiB)

typedef __attribute__((ext_vector_type(8))) short short8v;
typedef __attribute__((ext_vector_type(8))) unsigned short ushort8v;
typedef __attribute__((ext_vector_type(4))) float f32x4;

#define GLOAD16(gp, lp) __builtin_amdgcn_global_load_lds( \
  (const __attribute__((address_space(1))) unsigned int*)(gp), \
  (__attribute__((address_space(3))) unsigned int*)(void*)(lp), 16, 0, 0)

__device__ inline float bf2f(unsigned short u) {
  return __uint_as_float(((unsigned)u) << 16);
}

// ---------------------------------------------------------------------------
// K0: M_bf16[a][k] (a = x-side col, k = y-side col), padded [146+][168].
//   a<132:  M[a][k] = sum_o ks_w[o][a] * qs_w[o][k]
//   a==132: u[k]    = sum_o qs_b[o] * ks_w[o][k]   (z col 132 = su)
//   a==133: v[k]    = sum_o ks_b[o] * qs_w[o][k]   (z col 133 = sv)
//   else 0. Also c = ks_b . qs_b (f32).
// ---------------------------------------------------------------------------
__global__ __launch_bounds__(256) void prep_kernel(
    const float* __restrict__ ks_w, const float* __restrict__ ks_b,
    const float* __restrict__ qs_w, const float* __restrict__ qs_b,
    unsigned short* __restrict__ Mb, float* __restrict__ cc) {
  int idx = blockIdx.x * 256 + threadIdx.x;
  if (idx >= MELEMS_) return;
  int a = idx / FSTRIDE_;
  int k = idx - a * FSTRIDE_;
  float val = 0.f;
  if (k < D_) {
    if (a < D_) {
      for (int o = 0; o < D_; ++o)
        val = fmaf(ks_w[o * D_ + a], qs_w[o * D_ + k], val);
    } else if (a == 132) {
      for (int o = 0; o < D_; ++o)
        val = fmaf(qs_b[o], ks_w[o * D_ + k], val);
    } else if (a == 133) {
      for (int o = 0; o < D_; ++o)
        val = fmaf(ks_b[o], qs_w[o * D_ + k], val);
    }
  }
  __hip_bfloat16 hb = __float2bfloat16(val);
  Mb[idx] = *(unsigned short*)&hb;
  if (idx == 0) {
    float s = 0.f;
    for (int o = 0; o < D_; ++o) s = fmaf(ks_b[o], qs_b[o], s);
    cc[0] = s;
  }
}

// ---------------------------------------------------------------------------
// K1 v2: 3x3 SAME conv + bias + L2-norm over W, write bf16 transposed flat.
// 576 threads: d = tid%144 (132 active), wq = tid/144 (w-quarter of 32).
// Weights in registers; input row window in tiny LDS read via wave-broadcast
// float4 loads; conv outputs held in 32 registers; ssq quad-reduced via LDS.
// ---------------------------------------------------------------------------
__global__ __launch_bounds__(576) void conv_norm_kernel(
    const float* __restrict__ img, const float* __restrict__ cw,
    const float* __restrict__ cb, unsigned short* __restrict__ flat) {
  int bid = blockIdx.x;
  int tid = threadIdx.x;
  if (bid >= B_ * H_) {
    // zero row 16384 of every batch (cols 0..131; pad cols never read w/ nonzero M)
    for (int i = tid; i < B_ * D_; i += 576) {
      int b = i / D_, d = i - (i / D_) * D_;
      flat[((size_t)b * RPB_ + HW_) * FSTRIDE_ + d] = 0;
    }
    return;
  }
  int b = bid >> 7, h = bid & 127;

  __shared__ __align__(16) float in_s[9][132];  // [c*3+kh][x], x = ww+1; 4752 B
  __shared__ float parts[4][144];
  __shared__ float nscale[144];

  // stage input rows h-1..h+1 (zero-padded); x in 1..128 valid, 0/129..131 zero
  for (int i = tid; i < 9 * 132; i += 576) {
    int ck = i / 132, x = i - ck * 132;
    int c = ck / 3, kh = ck - c * 3;
    int hh = h + kh - 1, ww = x - 1;
    float val = 0.f;
    if (x >= 1 && x <= 128 && hh >= 0 && hh < H_)
      val = img[((size_t)(b * C_ + c) * H_ + hh) * W_ + ww];
    in_s[ck][x] = val;
  }
  __syncthreads();

  int d = tid % 144;
  int wq = tid / 144;
  int w0 = wq * 32;
  bool active = (d < D_);

  float wt[9][3];
  float bias = 0.f;
  if (active) {
    bias = cb[d];
    const float* wp = cw + d * 27;
#pragma unroll
    for (int ck = 0; ck < 9; ++ck)
#pragma unroll
      for (int kw = 0; kw < 3; ++kw)
        wt[ck][kw] = wp[ck * 3 + kw];
  } else {
#pragma unroll
    for (int ck = 0; ck < 9; ++ck)
#pragma unroll
      for (int kw = 0; kw < 3; ++kw)
        wt[ck][kw] = 0.f;
  }

  float acc[32];
#pragma unroll
  for (int i = 0; i < 32; ++i) acc[i] = bias;

#pragma unroll
  for (int ck = 0; ck < 9; ++ck) {
    const float4* p4 = (const float4*)&in_s[ck][0];  // row = 528 B = 33*16
    float v[36];
#pragma unroll
    for (int j = 0; j < 9; ++j) {
      float4 q = p4[(w0 >> 2) + j];   // wave-broadcast (all lanes same wq)
      v[4 * j + 0] = q.x; v[4 * j + 1] = q.y;
      v[4 * j + 2] = q.z; v[4 * j + 3] = q.w;
    }
    float w0c = wt[ck][0], w1c = wt[ck][1], w2c = wt[ck][2];
#pragma unroll
    for (int i = 0; i < 32; ++i) {
      float a0 = fmaf(v[i], w0c, acc[i]);
      float a1 = fmaf(v[i + 1], w1c, a0);
      acc[i] = fmaf(v[i + 2], w2c, a1);
    }
  }

  float ssq = 0.f;
#pragma unroll
  for (int i = 0; i < 32; ++i) ssq = fmaf(acc[i], acc[i], ssq);
  parts[wq][d] = ssq;
  __syncthreads();
  if (tid < 144) {
    float s = parts[0][tid] + parts[1][tid] + parts[2][tid] + parts[3][tid];
    nscale[tid] = 1.f / fmaxf(sqrtf(s), 1e-12f);
  }
  __syncthreads();

  if (active) {
    float sc = nscale[d];
    size_t rowbase = (size_t)b * RPB_ + (size_t)h * W_ + w0;
#pragma unroll
    for (int i = 0; i < 32; ++i) {
      __hip_bfloat16 hb = __float2bfloat16(acc[i] * sc);
      flat[(rowbase + i) * FSTRIDE_ + d] = *(unsigned short*)&hb;
    }
  }
}

// ---------------------------------------------------------------------------
// K2: MFMA GEMM. z[r][c] = sum_k flat[r][k] * M[c][k]  (c<132),
//     su[r] = z-col 132, sv[r] = z-col 133.
// ---------------------------------------------------------------------------
__global__ __launch_bounds__(256, 2) void gemm_kernel(
    const unsigned short* __restrict__ fb, const unsigned short* __restrict__ Mb,
    float* __restrict__ z, float* __restrict__ su, float* __restrict__ sv) {
  __shared__ unsigned short As[64 * FSTRIDE_];  // 21504 B
  __shared__ unsigned short Ms[MELEMS_];        // 49152 B
  int tid = threadIdx.x, wave = tid >> 6, lane = tid & 63;
  size_t row0 = (size_t)blockIdx.x * 64;

  for (int ch = wave; ch < 48; ch += 4)
    GLOAD16(Mb + (size_t)ch * 512 + lane * 8, Ms + ch * 512);
  const unsigned short* Ag = fb + row0 * FSTRIDE_;
  for (int ch = wave; ch < 21; ch += 4)
    GLOAD16(Ag + (size_t)ch * 512 + lane * 8, As + ch * 512);
  __syncthreads();

  int c15 = lane & 15, kg = lane >> 4;
  const unsigned short* arow = &As[(wave * 16 + c15) * FSTRIDE_ + kg * 8];
  const unsigned short* brow = &Ms[c15 * FSTRIDE_ + kg * 8];
  f32x4 acc[9] = {};
#pragma unroll
  for (int ks = 0; ks < 5; ++ks) {
    short8v af = *(const short8v*)(arow + ks * 32);
#pragma unroll
    for (int ct = 0; ct < 9; ++ct) {
      short8v bf = *(const short8v*)(brow + ct * 16 * FSTRIDE_ + ks * 32);
      acc[ct] = __builtin_amdgcn_mfma_f32_16x16x32_bf16(af, bf, acc[ct], 0, 0, 0);
    }
  }

  size_t rbase = row0 + wave * 16 + kg * 4;
#pragma unroll
  for (int ct = 0; ct < 9; ++ct) {
    int col = ct * 16 + c15;
#pragma unroll
    for (int j = 0; j < 4; ++j) {
      size_t r = rbase + j;
      if (r < NROWS_) {
        if (col < ZSTRIDE_)      z[r * ZSTRIDE_ + col] = acc[ct][j];
        else if (col == 132)     su[r] = acc[ct][j];
        else if (col == 133)     sv[r] = acc[ct][j];
      }
    }
  }
}

// ---------------------------------------------------------------------------
// K3: gather + dot. 8 lanes per output.
// out = (flat_bf16[x] . z[y] + su[x] + sv[y] + c) * 132^-0.5
// ---------------------------------------------------------------------------
__global__ __launch_bounds__(256) void gather_kernel(
    const int* __restrict__ xi, const int* __restrict__ yi,
    const unsigned short* __restrict__ flat, const float* __restrict__ z,
    const float* __restrict__ su, const float* __restrict__ sv,
    const float* __restrict__ cc, float* __restrict__ out) {
  const float scale = 0.08703882797784892f;  // 132^-0.5
  int o = blockIdx.x * 32 + (threadIdx.x >> 3);
  int lane = threadIdx.x & 7;
  int b = o >> 16;
  int rem = o & 65535;
  size_t ib = (size_t)b * NK_ + rem;
  int x = xi[ib], y = yi[ib];
  size_t rx = (size_t)b * RPB_ + x;
  size_t ry = (size_t)b * RPB_ + y;
  const unsigned short* fx = flat + rx * FSTRIDE_;
  const float* zy = z + ry * ZSTRIDE_;
  float acc = 0.f;
#pragma unroll
  for (int leg = 0; leg < 2; ++leg) {
    int e0 = leg * 64 + lane * 8;
    ushort8v a8 = *(const ushort8v*)(fx + e0);
    float4 z0 = *(const float4*)(zy + e0);
    float4 z1 = *(const float4*)(zy + e0 + 4);
    acc = fmaf(bf2f(a8[0]), z0.x, acc);
    acc = fmaf(bf2f(a8[1]), z0.y, acc);
    acc = fmaf(bf2f(a8[2]), z0.z, acc);
    acc = fmaf(bf2f(a8[3]), z0.w, acc);
    acc = fmaf(bf2f(a8[4]), z1.x, acc);
    acc = fmaf(bf2f(a8[5]), z1.y, acc);
    acc = fmaf(bf2f(a8[6]), z1.z, acc);
    acc = fmaf(bf2f(a8[7]), z1.w, acc);
  }
  if (lane == 0) {  // elems 128..131
    ushort8v a8 = *(const ushort8v*)(fx + 128);
    float4 z0 = *(const float4*)(zy + 128);
    acc = fmaf(bf2f(a8[0]), z0.x, acc);
    acc = fmaf(bf2f(a8[1]), z0.y, acc);
    acc = fmaf(bf2f(a8[2]), z0.z, acc);
    acc = fmaf(bf2f(a8[3]), z0.w, acc);
  }
  acc += __shfl_xor(acc, 1);
  acc += __shfl_xor(acc, 2);
  acc += __shfl_xor(acc, 4);
  if (lane == 0)
    out[o] = (acc + su[rx] + sv[ry] + cc[0]) * scale;
}

// ---------------------------------------------------------------------------
extern "C" void kernel_launch(void* const* d_in, const int* in_sizes, int n_in,
                              void* d_out, int out_size, void* d_ws, size_t ws_size,
                              hipStream_t stream) {
  const int* indices  = (const int*)d_in[0];
  const float* img    = (const float*)d_in[1];
  const float* conv_w = (const float*)d_in[2];
  const float* conv_b = (const float*)d_in[3];
  const float* ks_w   = (const float*)d_in[4];
  const float* ks_b   = (const float*)d_in[5];
  const float* qs_w   = (const float*)d_in[6];
  const float* qs_b   = (const float*)d_in[7];
  float* out = (float*)d_out;

  // workspace layout (~114.4 MB)
  char* w = (char*)d_ws;
  unsigned short* flatb = (unsigned short*)w;                 // AROWS_*168 bf16
  size_t off = (size_t)AROWS_ * FSTRIDE_ * 2;
  float* z = (float*)(w + off);  off += (size_t)NROWS_ * ZSTRIDE_ * 4;
  float* su = (float*)(w + off); off += (size_t)NROWS_ * 4;
  float* sv = (float*)(w + off); off += (size_t)NROWS_ * 4;
  unsigned short* Mb = (unsigned short*)(w + off); off += MELEMS_ * 2;
  float* cc = (float*)(w + off);

  const int* xi = indices + (size_t)B_ * NK_;      // indices[1]
  const int* yi = indices + (size_t)2 * B_ * NK_;  // indices[2]

  hipLaunchKernelGGL(prep_kernel, dim3(MELEMS_ / 256), dim3(256), 0, stream,
                     ks_w, ks_b, qs_w, qs_b, Mb, cc);
  hipLaunchKernelGGL(conv_norm_kernel, dim3(B_ * H_ + 1), dim3(576), 0, stream,
                     img, conv_w, conv_b, flatb);
  hipLaunchKernelGGL(gemm_kernel, dim3((NROWS_ + 63) / 64), dim3(256), 0, stream,
                     flatb, Mb, z, su, sv);
  hipLaunchKernelGGL(gather_kernel, dim3(NOUT_ / 32), dim3(256), 0, stream,
                     xi, yi, flatb, z, su, sv, cc, out);
}

// Round 5
// 106.136 us; speedup vs baseline: 4.0202x; 1.1737x over previous
//
#include <hip/hip_runtime.h>
#include <hip/hip_bf16.h>
#include <math.h>

#define B_ 8
#define H_ 128
#define W_ 128
#define C_ 3
#define D_ 132
#define HW_ (H_*W_)            // 16384
#define RPB_ (HW_+1)           // 16385 rows per batch (incl. zero row)
#define NROWS_ (B_*RPB_)       // 131080
#define AROWS_ 131136          // 2049*64, slack so last tile can stage
#define FSTRIDE_ 136           // bf16 row stride for flat_ext AND z_ext (272 B)
#define MSTRIDE_ 168           // M row stride (zeros at k>=132)
#define NK_ 65536
#define NOUT_ (B_*NK_)         // 524288
#define MELEMS_ 24576          // M buffer elems (49152 B = 48 chunks of 1 KiB)

typedef __attribute__((ext_vector_type(8))) short short8v;
typedef __attribute__((ext_vector_type(8))) unsigned short ushort8v;
typedef __attribute__((ext_vector_type(4))) float f32x4;

#define GLOAD16(gp, lp) __builtin_amdgcn_global_load_lds( \
  (const __attribute__((address_space(1))) unsigned int*)(gp), \
  (__attribute__((address_space(3))) unsigned int*)(void*)(lp), 16, 0, 0)

__device__ inline float bf2f(unsigned short u) {
  return __uint_as_float(((unsigned)u) << 16);
}
__device__ inline unsigned short f2bf(float f) {
  __hip_bfloat16 hb = __float2bfloat16(f);
  return *(unsigned short*)&hb;
}

// ---------------------------------------------------------------------------
// K0: M_bf16[a][k], padded [146][168].
//   a<132:  M[a][k] = sum_o ks_w[o][a] * qs_w[o][k]
//   a==132: u[k] (z col 132 = su);  a==133: v[k] (z col 133 = sv); else 0.
//   c = ks_b . qs_b (f32).
// ---------------------------------------------------------------------------
__global__ __launch_bounds__(256) void prep_kernel(
    const float* __restrict__ ks_w, const float* __restrict__ ks_b,
    const float* __restrict__ qs_w, const float* __restrict__ qs_b,
    unsigned short* __restrict__ Mb, float* __restrict__ cc) {
  int idx = blockIdx.x * 256 + threadIdx.x;
  if (idx >= MELEMS_) return;
  int a = idx / MSTRIDE_;
  int k = idx - a * MSTRIDE_;
  float val = 0.f;
  if (k < D_) {
    if (a < D_) {
      for (int o = 0; o < D_; ++o)
        val = fmaf(ks_w[o * D_ + a], qs_w[o * D_ + k], val);
    } else if (a == 132) {
      for (int o = 0; o < D_; ++o)
        val = fmaf(qs_b[o], ks_w[o * D_ + k], val);
    } else if (a == 133) {
      for (int o = 0; o < D_; ++o)
        val = fmaf(ks_b[o], qs_w[o * D_ + k], val);
    }
  }
  Mb[idx] = f2bf(val);
  if (idx == 0) {
    float s = 0.f;
    for (int o = 0; o < D_; ++o) s = fmaf(ks_b[o], qs_b[o], s);
    cc[0] = s;
  }
}

// ---------------------------------------------------------------------------
// K1: 3x3 SAME conv + bias + L2-norm over W, write bf16 flat_ext rows:
// [f(132), 1.0, 0(su placeholder), 0, 0], stride 136.
// 576 threads: d = tid%144, wq = tid/144 (w-quarter of 32).
// NOTE: inactive lanes write ONLY d in 132..135 — d>=136 would overrun into
// the NEXT row's elements 0..7 and race with its owners (round-4 bug).
// ---------------------------------------------------------------------------
__global__ __launch_bounds__(576) void conv_norm_kernel(
    const float* __restrict__ img, const float* __restrict__ cw,
    const float* __restrict__ cb, unsigned short* __restrict__ flat) {
  int bid = blockIdx.x;
  int tid = threadIdx.x;
  if (bid >= B_ * H_) {
    // zero row 16384 of every batch: [0 x132, 1.0, 0, 0, 0]
    for (int i = tid; i < B_ * FSTRIDE_; i += 576) {
      int b = i / FSTRIDE_, d = i - (i / FSTRIDE_) * FSTRIDE_;
      flat[((size_t)b * RPB_ + HW_) * FSTRIDE_ + d] = (d == 132) ? 0x3F80 : 0;
    }
    return;
  }
  int b = bid >> 7, h = bid & 127;

  __shared__ __align__(16) float in_s[9][132];
  __shared__ float parts[4][144];
  __shared__ float nscale[144];

  for (int i = tid; i < 9 * 132; i += 576) {
    int ck = i / 132, x = i - ck * 132;
    int c = ck / 3, kh = ck - c * 3;
    int hh = h + kh - 1, ww = x - 1;
    float val = 0.f;
    if (x >= 1 && x <= 128 && hh >= 0 && hh < H_)
      val = img[((size_t)(b * C_ + c) * H_ + hh) * W_ + ww];
    in_s[ck][x] = val;
  }
  __syncthreads();

  int d = tid % 144;
  int wq = tid / 144;
  int w0 = wq * 32;
  bool active = (d < D_);

  float wt[9][3];
  float bias = 0.f;
  if (active) {
    bias = cb[d];
    const float* wp = cw + d * 27;
#pragma unroll
    for (int ck = 0; ck < 9; ++ck)
#pragma unroll
      for (int kw = 0; kw < 3; ++kw)
        wt[ck][kw] = wp[ck * 3 + kw];
  } else {
#pragma unroll
    for (int ck = 0; ck < 9; ++ck)
#pragma unroll
      for (int kw = 0; kw < 3; ++kw)
        wt[ck][kw] = 0.f;
  }

  float acc[32];
#pragma unroll
  for (int i = 0; i < 32; ++i) acc[i] = bias;

#pragma unroll
  for (int ck = 0; ck < 9; ++ck) {
    const float4* p4 = (const float4*)&in_s[ck][0];
    float v[36];
#pragma unroll
    for (int j = 0; j < 9; ++j) {
      float4 q = p4[(w0 >> 2) + j];   // wave-broadcast
      v[4 * j + 0] = q.x; v[4 * j + 1] = q.y;
      v[4 * j + 2] = q.z; v[4 * j + 3] = q.w;
    }
    float w0c = wt[ck][0], w1c = wt[ck][1], w2c = wt[ck][2];
#pragma unroll
    for (int i = 0; i < 32; ++i) {
      float a0 = fmaf(v[i], w0c, acc[i]);
      float a1 = fmaf(v[i + 1], w1c, a0);
      acc[i] = fmaf(v[i + 2], w2c, a1);
    }
  }

  float ssq = 0.f;
#pragma unroll
  for (int i = 0; i < 32; ++i) ssq = fmaf(acc[i], acc[i], ssq);
  parts[wq][d] = ssq;
  __syncthreads();
  if (tid < 144) {
    float s = parts[0][tid] + parts[1][tid] + parts[2][tid] + parts[3][tid];
    nscale[tid] = 1.f / fmaxf(sqrtf(s), 1e-12f);
  }
  __syncthreads();

  size_t rowbase = (size_t)b * RPB_ + (size_t)h * W_ + w0;
  if (active) {
    float sc = nscale[d];
#pragma unroll
    for (int i = 0; i < 32; ++i)
      flat[(rowbase + i) * FSTRIDE_ + d] = f2bf(acc[i] * sc);
  } else if (d < FSTRIDE_) {  // d in 132..135 ONLY (fix: no next-row overrun)
    unsigned short cval = (d == 132) ? 0x3F80 : 0;  // 1.0 at 132; 0 at 133..135
#pragma unroll
    for (int i = 0; i < 32; ++i)
      flat[(rowbase + i) * FSTRIDE_ + d] = cval;
  }
}

// ---------------------------------------------------------------------------
// K2: MFMA GEMM -> bf16 z_ext rows [z(132), sv+c, 1.0, 0, 0], and writes
// su back into flat_ext col 133.
// 64 rows/block, 4 waves x (16 rows x 144 cols), K = 5 slices of 32
// (slices cover k 0..159: A k>=136 wraps into next row, M is zero there).
// ---------------------------------------------------------------------------
__global__ __launch_bounds__(256, 2) void gemm_kernel(
    unsigned short* __restrict__ fb, const unsigned short* __restrict__ Mb,
    const float* __restrict__ cc, unsigned short* __restrict__ zb) {
  __shared__ __align__(16) unsigned short As[64 * FSTRIDE_ + 64];  // +tail pad
  __shared__ __align__(16) unsigned short Ms[MELEMS_];
  int tid = threadIdx.x, wave = tid >> 6, lane = tid & 63;
  size_t row0 = (size_t)blockIdx.x * 64;

  // stage M: 48 KiB; A: 17 KiB (272 B/row x 64)
  for (int ch = wave; ch < 48; ch += 4)
    GLOAD16(Mb + (size_t)ch * 512 + lane * 8, Ms + ch * 512);
  const unsigned short* Ag = fb + row0 * FSTRIDE_;
  for (int ch = wave; ch < 17; ch += 4)
    GLOAD16(Ag + (size_t)ch * 512 + lane * 8, As + ch * 512);
  if (tid < 64) As[64 * FSTRIDE_ + tid] = 0;  // tail: slice-5 OOB reads
  __syncthreads();

  int c15 = lane & 15, kg = lane >> 4;
  const unsigned short* arow = &As[(wave * 16 + c15) * FSTRIDE_ + kg * 8];
  const unsigned short* brow = &Ms[c15 * MSTRIDE_ + kg * 8];
  f32x4 acc[9] = {};
#pragma unroll
  for (int ks = 0; ks < 5; ++ks) {
    short8v af = *(const short8v*)(arow + ks * 32);
#pragma unroll
    for (int ct = 0; ct < 9; ++ct) {
      short8v bf = *(const short8v*)(brow + ct * 16 * MSTRIDE_ + ks * 32);
      acc[ct] = __builtin_amdgcn_mfma_f32_16x16x32_bf16(af, bf, acc[ct], 0, 0, 0);
    }
  }

  float cval = cc[0];
  // C/D layout: col = lane&15 (+16*ct), row = kg*4 + reg
  size_t rbase = row0 + wave * 16 + kg * 4;
#pragma unroll
  for (int ct = 0; ct < 9; ++ct) {
    int col = ct * 16 + c15;
#pragma unroll
    for (int j = 0; j < 4; ++j) {
      size_t r = rbase + j;
      if (r < NROWS_) {
        if (col < D_)            zb[r * FSTRIDE_ + col] = f2bf(acc[ct][j]);
        else if (col == 132)     fb[r * FSTRIDE_ + 133] = f2bf(acc[ct][j]);        // su
        else if (col == 133)     zb[r * FSTRIDE_ + 132] = f2bf(acc[ct][j] + cval); // sv+c
        else if (col == 134)     zb[r * FSTRIDE_ + 133] = 0x3F80;                  // 1.0
        else if (col == 135)     zb[r * FSTRIDE_ + 134] = 0;
        else if (col == 136)     zb[r * FSTRIDE_ + 135] = 0;
      }
    }
  }
}

// ---------------------------------------------------------------------------
// K3: gather + dot, both sides bf16 136-elem rows. 8 lanes per output.
// out = (fx_ext . zy_ext) * 132^-0.5   (su/sv/c folded into the rows)
// ---------------------------------------------------------------------------
__global__ __launch_bounds__(256) void gather_kernel(
    const int* __restrict__ xi, const int* __restrict__ yi,
    const unsigned short* __restrict__ flat, const unsigned short* __restrict__ zb,
    float* __restrict__ out) {
  const float scale = 0.08703882797784892f;  // 132^-0.5
  int o = blockIdx.x * 32 + (threadIdx.x >> 3);
  int lane = threadIdx.x & 7;
  int b = o >> 16;
  int rem = o & 65535;
  size_t ib = (size_t)b * NK_ + rem;
  int x = xi[ib], y = yi[ib];
  const unsigned short* fx = flat + ((size_t)b * RPB_ + x) * FSTRIDE_;
  const unsigned short* zy = zb + ((size_t)b * RPB_ + y) * FSTRIDE_;
  float acc = 0.f;
#pragma unroll
  for (int leg = 0; leg < 2; ++leg) {
    int e0 = leg * 64 + lane * 8;
    ushort8v a8 = *(const ushort8v*)(fx + e0);
    ushort8v z8 = *(const ushort8v*)(zy + e0);
#pragma unroll
    for (int t = 0; t < 8; ++t)
      acc = fmaf(bf2f(a8[t]), bf2f(z8[t]), acc);
  }
  if (lane == 0) {  // elems 128..135: real 128..131 + (1)(sv+c) + (su)(1) + 0s
    ushort8v a8 = *(const ushort8v*)(fx + 128);
    ushort8v z8 = *(const ushort8v*)(zy + 128);
#pragma unroll
    for (int t = 0; t < 8; ++t)
      acc = fmaf(bf2f(a8[t]), bf2f(z8[t]), acc);
  }
  acc += __shfl_xor(acc, 1);
  acc += __shfl_xor(acc, 2);
  acc += __shfl_xor(acc, 4);
  if (lane == 0)
    out[o] = acc * scale;
}

// ---------------------------------------------------------------------------
extern "C" void kernel_launch(void* const* d_in, const int* in_sizes, int n_in,
                              void* d_out, int out_size, void* d_ws, size_t ws_size,
                              hipStream_t stream) {
  const int* indices  = (const int*)d_in[0];
  const float* img    = (const float*)d_in[1];
  const float* conv_w = (const float*)d_in[2];
  const float* conv_b = (const float*)d_in[3];
  const float* ks_w   = (const float*)d_in[4];
  const float* ks_b   = (const float*)d_in[5];
  const float* qs_w   = (const float*)d_in[6];
  const float* qs_b   = (const float*)d_in[7];
  float* out = (float*)d_out;

  // workspace layout (~71.5 MB)
  char* w = (char*)d_ws;
  unsigned short* flatb = (unsigned short*)w;                  // AROWS_*136 bf16
  size_t off = (size_t)AROWS_ * FSTRIDE_ * 2;
  unsigned short* zbuf = (unsigned short*)(w + off); off += (size_t)AROWS_ * FSTRIDE_ * 2;
  unsigned short* Mb = (unsigned short*)(w + off);   off += MELEMS_ * 2;
  float* cc = (float*)(w + off);

  const int* xi = indices + (size_t)B_ * NK_;      // indices[1]
  const int* yi = indices + (size_t)2 * B_ * NK_;  // indices[2]

  hipLaunchKernelGGL(prep_kernel, dim3(MELEMS_ / 256), dim3(256), 0, stream,
                     ks_w, ks_b, qs_w, qs_b, Mb, cc);
  hipLaunchKernelGGL(conv_norm_kernel, dim3(B_ * H_ + 1), dim3(576), 0, stream,
                     img, conv_w, conv_b, flatb);
  hipLaunchKernelGGL(gemm_kernel, dim3(AROWS_ / 64), dim3(256), 0, stream,
                     flatb, Mb, cc, zbuf);
  hipLaunchKernelGGL(gather_kernel, dim3(NOUT_ / 32), dim3(256), 0, stream,
                     xi, yi, flatb, zbuf, out);
}